// Round 1
// baseline (706.640 us; speedup 1.0000x reference)
//
#include <hip/hip_runtime.h>
#include <hip/hip_fp16.h>

#define FD 128            // feature dim
#define BSHIFT 9          // bucket = dst >> 9  (512 nodes per bucket)
#define BNODES 512
#define CAP 20480         // per-bucket capacity (avg 16.3K + >30 sigma)
#define SBLK 1024         // scatter blocks

typedef _Float16 half8 __attribute__((ext_vector_type(8)));
typedef float floatx4 __attribute__((ext_vector_type(4)));

// ---------------------------------------------------------------------------
// fp32 -> f16 row-major feature conversion (x only, once per call)
// ---------------------------------------------------------------------------
__global__ __launch_bounds__(256) void to_f16_kernel(const float4* __restrict__ in,
                                                     __half2* __restrict__ out, int n4) {
    int i = blockIdx.x * 256 + threadIdx.x;
    if (i < n4) {
        float4 v = in[i];
        out[2 * i + 0] = __floats2half2_rn(v.x, v.y);
        out[2 * i + 1] = __floats2half2_rn(v.z, v.w);
    }
}

// ---------------------------------------------------------------------------
// Pack all 3 layers' [Wl;Wr] into MFMA B-frag order (one launch, 48 blocks).
// frag_idx = layer*4096 + (nt*8 + kt)*64 + lane; B[k][n], n=nt*16+(lane&15),
// k=kt*32+(lane>>4)*8+j.
// ---------------------------------------------------------------------------
__global__ __launch_bounds__(256) void pack_w3_kernel(const float* __restrict__ W1l,
                                                      const float* __restrict__ W1r,
                                                      const float* __restrict__ W2l,
                                                      const float* __restrict__ W2r,
                                                      const float* __restrict__ W3l,
                                                      const float* __restrict__ W3r,
                                                      half8* __restrict__ out) {
    int t = blockIdx.x * 256 + threadIdx.x;   // 0..12287
    int layer = t >> 12;
    int li = t & 4095;
    const float* Wl = (layer == 0) ? W1l : (layer == 1) ? W2l : W3l;
    const float* Wr = (layer == 0) ? W1r : (layer == 1) ? W2r : W3r;
    int lane = li & 63;
    int kt = (li >> 6) & 7;
    int nt = li >> 9;
    int n = nt * 16 + (lane & 15);
    int kq = kt * 32 + ((lane >> 4) & 3) * 8;
    half8 f;
#pragma unroll
    for (int j = 0; j < 8; ++j) {
        int k = kq + j;
        float v = (k < 128) ? Wl[n * 128 + k] : Wr[n * 128 + (k - 128)];
        f[j] = (_Float16)v;
    }
    out[t] = f;
}

// ---------------------------------------------------------------------------
// Bucketed scatter with block-level reservation. Each block handles a
// contiguous edge chunk: LDS histogram -> one global atomicAdd per
// (block,bucket) to reserve a range in sorted[b*CAP ...] -> scatter.
// ---------------------------------------------------------------------------
__global__ __launch_bounds__(256) void scatter_kernel(const int* __restrict__ src,
                                                      const int* __restrict__ dst,
                                                      int* __restrict__ cursor,
                                                      int2* __restrict__ sorted, int E) {
    __shared__ int cnt[256];
    __shared__ int base[256];
    int t = threadIdx.x;
    cnt[t] = 0;
    __syncthreads();
    int chunk = (E + SBLK - 1) / SBLK;
    int s0 = blockIdx.x * chunk;
    int s1 = s0 + chunk; if (s1 > E) s1 = E;
    for (int e = s0 + t; e < s1; e += 256)
        atomicAdd(&cnt[dst[e] >> BSHIFT], 1);
    __syncthreads();
    int c = cnt[t];
    if (c > 0) base[t] = atomicAdd(&cursor[t], c);
    cnt[t] = 0;
    __syncthreads();
    for (int e = s0 + t; e < s1; e += 256) {
        int d = dst[e];
        int b = d >> BSHIFT;
        int p = base[b] + atomicAdd(&cnt[b], 1);
        if (p < CAP) sorted[(size_t)b * CAP + p] = make_int2(src[e], d);
    }
}

// ---------------------------------------------------------------------------
// Per-bucket CSR build: degree (LDS atomics) -> LDS 512-scan -> row_ptr/deg/
// rdeg -> LDS-cursor fill. row_ptr is absolute into csr[b*CAP + ...]; holes
// between buckets are harmless.
// ---------------------------------------------------------------------------
__global__ __launch_bounds__(256) void bucket_build(const int2* __restrict__ sorted,
                                                    const int* __restrict__ cursor,
                                                    int* __restrict__ row_ptr,
                                                    int* __restrict__ deg,
                                                    float* __restrict__ rdeg,
                                                    int* __restrict__ csr, int N) {
    __shared__ int dl[BNODES];
    __shared__ int ps[256];
    int b = blockIdx.x;
    int nbase = b << BSHIFT;
    int t = threadIdx.x;
    int cnt = cursor[b]; if (cnt > CAP) cnt = CAP;
    dl[t] = 0; dl[t + 256] = 0;
    __syncthreads();
    const int2* se = sorted + (size_t)b * CAP;
    for (int e = t; e < cnt; e += 256)
        atomicAdd(&dl[se[e].y - nbase], 1);
    __syncthreads();
    int a0 = dl[2 * t], a1 = dl[2 * t + 1];
    ps[t] = a0 + a1;
    __syncthreads();
    for (int off = 1; off < 256; off <<= 1) {
        int v = (t >= off) ? ps[t - off] : 0;
        __syncthreads();
        ps[t] += v;
        __syncthreads();
    }
    int pre = ps[t] - a0 - a1;               // exclusive prefix of element 2t
    int cb = b * CAP;
    int n0 = nbase + 2 * t, n1 = n0 + 1;
    if (n0 < N) {
        row_ptr[n0] = cb + pre;
        deg[n0] = a0;
        rdeg[n0] = 1.0f / (float)(a0 > 1 ? a0 : 1);
    }
    if (n1 < N) {
        row_ptr[n1] = cb + pre + a0;
        deg[n1] = a1;
        rdeg[n1] = 1.0f / (float)(a1 > 1 ? a1 : 1);
    }
    dl[2 * t] = pre;
    dl[2 * t + 1] = pre + a0;
    __syncthreads();
    for (int e = t; e < cnt; e += 256) {
        int2 ed = se[e];
        int p = atomicAdd(&dl[ed.y - nbase], 1);
        csr[cb + p] = ed.x;
    }
}

// ---------------------------------------------------------------------------
// Mean aggregation (R5 layout): one wave per dst node; each 16-lane group
// handles one edge with half8 (16 B) loads -> 4 edges per VMEM instruction,
// 4x fewer gather instructions than the half2 variant. Main loop keeps 16
// edges (4 KB) in flight per wave. Cross-group reduce via __shfl_xor(16,32).
// fp32 accumulate, f16 output (group 0 stores the 256 B row).
// ---------------------------------------------------------------------------
__global__ __launch_bounds__(256) void agg_kernel(const __half* __restrict__ h,
                                                  const int* __restrict__ row_ptr,
                                                  const int* __restrict__ deg,
                                                  const float* __restrict__ rdeg,
                                                  const int* __restrict__ csr,
                                                  __half* __restrict__ out, int n) {
    int node = (blockIdx.x * 256 + threadIdx.x) >> 6;
    int lane = threadIdx.x & 63;
    if (node >= n) return;
    int g = lane >> 4;        // edge slot 0..3 within wave
    int l16 = lane & 15;      // 16B chunk within 256B row
    int start = row_ptr[node];
    int d = deg[node];
    float acc[8];
#pragma unroll
    for (int j = 0; j < 8; ++j) acc[j] = 0.f;

    int i = 0;
    for (; i + 16 <= d; i += 16) {                 // 4 loads in flight / wave
        int s0 = csr[start + i + 0 + g];
        int s1 = csr[start + i + 4 + g];
        int s2 = csr[start + i + 8 + g];
        int s3 = csr[start + i + 12 + g];
        half8 v0 = *(const half8*)(h + (size_t)s0 * FD + l16 * 8);
        half8 v1 = *(const half8*)(h + (size_t)s1 * FD + l16 * 8);
        half8 v2 = *(const half8*)(h + (size_t)s2 * FD + l16 * 8);
        half8 v3 = *(const half8*)(h + (size_t)s3 * FD + l16 * 8);
#pragma unroll
        for (int j = 0; j < 8; ++j) acc[j] += (float)v0[j];
#pragma unroll
        for (int j = 0; j < 8; ++j) acc[j] += (float)v1[j];
#pragma unroll
        for (int j = 0; j < 8; ++j) acc[j] += (float)v2[j];
#pragma unroll
        for (int j = 0; j < 8; ++j) acc[j] += (float)v3[j];
    }
    for (; i + 4 <= d; i += 4) {
        int s = csr[start + i + g];
        half8 v = *(const half8*)(h + (size_t)s * FD + l16 * 8);
#pragma unroll
        for (int j = 0; j < 8; ++j) acc[j] += (float)v[j];
    }
    if (i + g < d) {                               // masked tail (d % 4)
        int s = csr[start + i + g];
        half8 v = *(const half8*)(h + (size_t)s * FD + l16 * 8);
#pragma unroll
        for (int j = 0; j < 8; ++j) acc[j] += (float)v[j];
    }

    // reduce the 4 edge slots: lanes differing in bits 4,5 hold the same
    // feature elements -> butterfly over xor 16, 32
#pragma unroll
    for (int j = 0; j < 8; ++j) {
        acc[j] += __shfl_xor(acc[j], 16, 64);
        acc[j] += __shfl_xor(acc[j], 32, 64);
    }

    if (g == 0) {
        float r = rdeg[node];
        half8 o;
#pragma unroll
        for (int j = 0; j < 8; ++j) o[j] = (_Float16)(acc[j] * r);
        *(half8*)(out + (size_t)node * FD + l16 * 8) = o;
    }
}

// ---------------------------------------------------------------------------
// MFMA GEMM (R4): out = cat(A,H) @ Wcat^T + b (+ReLU). Row-major f16 in.
// mfma_f32_16x16x32_f16: A[m=lane&15][k=quad*8+j], C/D col=lane&15,
// row=quad*4+reg. No LDS, no barriers.
// ---------------------------------------------------------------------------
template <int OUT_FP32>
__global__ __launch_bounds__(256) void gemm_mfma(const __half* __restrict__ A,
                                                 const __half* __restrict__ H,
                                                 const half8* __restrict__ Wfrag,
                                                 const float* __restrict__ bias,
                                                 void* outp, int n, int do_relu) {
    int tid = threadIdx.x;
    int wave = tid >> 6;
    int lane = tid & 63;
    int quad = (lane >> 4) & 3;
    int l16 = lane & 15;
    long tilebase = (long)blockIdx.x * 128;
    long r0 = tilebase + wave * 32 + l16;
    long r1 = r0 + 16;
    long ra = (r0 < n) ? r0 : (n - 1);
    long rb = (r1 < n) ? r1 : (n - 1);

    floatx4 acc[2][8];
#pragma unroll
    for (int m = 0; m < 2; ++m)
#pragma unroll
        for (int nt = 0; nt < 8; ++nt) acc[m][nt] = (floatx4){0.f, 0.f, 0.f, 0.f};

#pragma unroll
    for (int kt = 0; kt < 8; ++kt) {
        const __half* src = (kt < 4) ? A : H;
        int koff = (kt & 3) * 32 + quad * 8;
        half8 a0 = *(const half8*)(src + (size_t)ra * FD + koff);
        half8 a1 = *(const half8*)(src + (size_t)rb * FD + koff);
#pragma unroll
        for (int nt = 0; nt < 8; ++nt) {
            half8 b = Wfrag[(size_t)(nt * 8 + kt) * 64 + lane];
            acc[0][nt] = __builtin_amdgcn_mfma_f32_16x16x32_f16(a0, b, acc[0][nt], 0, 0, 0);
            acc[1][nt] = __builtin_amdgcn_mfma_f32_16x16x32_f16(a1, b, acc[1][nt], 0, 0, 0);
        }
    }

#pragma unroll
    for (int m = 0; m < 2; ++m) {
#pragma unroll
        for (int nt = 0; nt < 8; ++nt) {
            int col = nt * 16 + l16;
            float bv = bias[col];
#pragma unroll
            for (int r = 0; r < 4; ++r) {
                long row = tilebase + wave * 32 + m * 16 + quad * 4 + r;
                if (row < n) {
                    float v = acc[m][nt][r] + bv;
                    if (do_relu) v = v > 0.f ? v : 0.f;
                    if (OUT_FP32)
                        ((float*)outp)[row * FD + col] = v;
                    else
                        ((__half*)outp)[row * FD + col] = __float2half_rn(v);
                }
            }
        }
    }
}

// ---------------------------------------------------------------------------
extern "C" void kernel_launch(void* const* d_in, const int* in_sizes, int n_in,
                              void* d_out, int out_size, void* d_ws, size_t ws_size,
                              hipStream_t stream) {
    const float* x   = (const float*)d_in[0];
    const int*   ei  = (const int*)d_in[1];
    const float* W1l = (const float*)d_in[2];
    const float* W1r = (const float*)d_in[3];
    const float* W2l = (const float*)d_in[4];
    const float* W2r = (const float*)d_in[5];
    const float* W3l = (const float*)d_in[6];
    const float* W3r = (const float*)d_in[7];
    const float* b1  = (const float*)d_in[8];
    const float* b2  = (const float*)d_in[9];
    const float* b3  = (const float*)d_in[10];
    float* out = (float*)d_out;

    int N = in_sizes[0] / FD;
    int E = in_sizes[1] / 2;
    const int* src = ei;
    const int* dst = ei + E;
    int B = (N + BNODES - 1) >> BSHIFT;   // 196 buckets

    char* ws = (char*)d_ws;
    size_t off = 0;
    auto alloc = [&](size_t bytes) -> void* {
        void* p = ws + off;
        off += (bytes + 255) & ~(size_t)255;
        return p;
    };
    int*    deg     = (int*)alloc((size_t)N * 4);
    int*    row_ptr = (int*)alloc((size_t)N * 4);
    float*  rdeg    = (float*)alloc((size_t)N * 4);
    int*    cursor  = (int*)alloc(256 * 4);
    int*    csr     = (int*)alloc((size_t)B * CAP * 4);
    __half* xb      = (__half*)alloc((size_t)N * FD * 2);
    __half* h1      = (__half*)alloc((size_t)N * FD * 2);
    __half* h2      = (__half*)alloc((size_t)N * FD * 2);
    __half* aggB    = (__half*)alloc((size_t)N * FD * 2);
    half8*  wf      = (half8*)alloc((size_t)3 * 4096 * 16);
    int2*   sorted  = (int2*)alloc((size_t)B * CAP * 8);

    // ---- conversions / weight packing / CSR build ----
    int n4 = N * FD / 4;
    to_f16_kernel<<<(n4 + 255) / 256, 256, 0, stream>>>((const float4*)x, (__half2*)xb, n4);
    pack_w3_kernel<<<48, 256, 0, stream>>>(W1l, W1r, W2l, W2r, W3l, W3r, wf);
    hipMemsetAsync(cursor, 0, 256 * 4, stream);
    scatter_kernel<<<SBLK, 256, 0, stream>>>(src, dst, cursor, sorted, E);
    bucket_build<<<B, 256, 0, stream>>>(sorted, cursor, row_ptr, deg, rdeg, csr, N);

    int aggGrid  = (N + 3) / 4;
    int gemmGrid = (N + 127) / 128;

    // layer 1
    agg_kernel<<<aggGrid, 256, 0, stream>>>(xb, row_ptr, deg, rdeg, csr, aggB, N);
    gemm_mfma<0><<<gemmGrid, 256, 0, stream>>>(aggB, xb, wf, b1, h1, N, 1);
    // layer 2
    agg_kernel<<<aggGrid, 256, 0, stream>>>(h1, row_ptr, deg, rdeg, csr, aggB, N);
    gemm_mfma<0><<<gemmGrid, 256, 0, stream>>>(aggB, h1, wf + 4096, b2, h2, N, 1);
    // layer 3 (no relu, fp32 out)
    agg_kernel<<<aggGrid, 256, 0, stream>>>(h2, row_ptr, deg, rdeg, csr, aggB, N);
    gemm_mfma<1><<<gemmGrid, 256, 0, stream>>>(aggB, h2, wf + 8192, b3, out, N, 0);
}